// Round 6
// baseline (214.492 us; speedup 1.0000x reference)
//
#include <hip/hip_runtime.h>

// 1 - alpha = (1 + exp(density+shift))^(-0.5) = rsqrt(u), u = 1 + exp(x).
// alpha * (1/(1-alpha)) = u*a - 1, so w = T_excl * alpha.

__device__ __forceinline__ float fast_sigmoid(float x) {
    return __builtin_amdgcn_rcpf(1.0f + __expf(-x));
}

struct __align__(4) f3 { float x, y, z; };   // 12B, 4B-aligned -> dwordx3

// ---- DPP wave64 scans ------------------------------------------------------
#define DPP_ADD(x, ctrl, rmask)                                               \
    do {                                                                      \
        int _s = __builtin_amdgcn_update_dpp(0, __float_as_int(x), (ctrl),    \
                                             (rmask), 0xf, true);             \
        (x) += __int_as_float(_s);                                            \
    } while (0)

#define DPP_MUL(x, ctrl, rmask)                                               \
    do {                                                                      \
        int _s = __builtin_amdgcn_update_dpp(0x3f800000, __float_as_int(x),   \
                                             (ctrl), (rmask), 0xf, false);    \
        (x) *= __int_as_float(_s);                                            \
    } while (0)

__device__ __forceinline__ float wave_scan_add(float x) {
    DPP_ADD(x, 0x111, 0xf);  // row_shr:1
    DPP_ADD(x, 0x112, 0xf);  // row_shr:2
    DPP_ADD(x, 0x114, 0xf);  // row_shr:4
    DPP_ADD(x, 0x118, 0xf);  // row_shr:8
    DPP_ADD(x, 0x142, 0xa);  // row_bcast:15 -> rows 1,3
    DPP_ADD(x, 0x143, 0xc);  // row_bcast:31 -> rows 2,3
    return x;
}

// Full-wave inclusive product scan.
__device__ __forceinline__ float wave_scan_mul(float x) {
    DPP_MUL(x, 0x111, 0xf);
    DPP_MUL(x, 0x112, 0xf);
    DPP_MUL(x, 0x114, 0xf);
    DPP_MUL(x, 0x118, 0xf);
    DPP_MUL(x, 0x142, 0xa);
    DPP_MUL(x, 0x143, 0xc);
    return x;
}

// Inclusive product scan SEGMENTED at the lane-31/32 boundary (first five DPP
// stages never cross 32-lane halves). Totals live in lanes 31 and 63.
__device__ __forceinline__ float wave_scan_mul_half(float x) {
    DPP_MUL(x, 0x111, 0xf);
    DPP_MUL(x, 0x112, 0xf);
    DPP_MUL(x, 0x114, 0xf);
    DPP_MUL(x, 0x118, 0xf);
    DPP_MUL(x, 0x142, 0xa);
    return x;
}

__device__ __forceinline__ float bcast_lane63(float x) {
    return __int_as_float(__builtin_amdgcn_readlane(__float_as_int(x), 63));
}
__device__ __forceinline__ float bcast_lane31(float x) {
    return __int_as_float(__builtin_amdgcn_readlane(__float_as_int(x), 31));
}

// ---- Pass 1: segment starts (int4-vectorized boundary detection) -----------
__global__ __launch_bounds__(256) void seg_starts4_kernel(
    const int4* __restrict__ ray4, int M4, int M, int N,
    const int* __restrict__ ray_id, int* __restrict__ starts)
{
    const int i = blockIdx.x * blockDim.x + threadIdx.x;
    if (i >= M4) return;
    const int4 v = ray4[i];
    const int prev = (i == 0) ? -1 : ray_id[4 * i - 1];
    const int base = 4 * i;
    for (int r = prev + 1; r <= v.x; ++r) starts[r] = base;
    for (int r = v.x + 1;  r <= v.y; ++r) starts[r] = base + 1;
    for (int r = v.y + 1;  r <= v.z; ++r) starts[r] = base + 2;
    for (int r = v.z + 1;  r <= v.w; ++r) starts[r] = base + 3;
    if (i == M4 - 1) {
        int last = v.w;
        for (int j = 4 * M4; j < M; ++j) {      // scalar tail (M%4)
            const int cur = ray_id[j];
            for (int r = last + 1; r <= cur; ++r) starts[r] = j;
            last = cur;
        }
        for (int r = last + 1; r <= N; ++r) starts[r] = M;
    }
}

// ---- Pass 2: RPW=8 rays per wave, paired-overflow chunks, deep ILP ---------
// Evidence R0-R5: time invariant to VALU work (+-33%) and to prefetch pinning;
// VALUBusy ~50%, HBM 21% -> per-wave exposed latency with convoy effects.
// Lever: 2x longer waves. 8 chunk-0 scans + 4 paired-overflow scans per wave,
// all branchless straight-line: 8-way independent DPP chains in Phase B,
// 48 loads issued in one burst (chunk0 first -> counted vmcnt releases
// Phase B while the 16 overflow loads are still in flight, hiding their
// latency under ~600 cycles of chunk-0 compute). Halves wave count.
#define RPW 8
#define NPAIR (RPW / 2)

__global__ __launch_bounds__(256, 4) void favor_render_kernel(
    const float* __restrict__ density,
    const float* __restrict__ rgb_feat,   // [M,3]
    const float* __restrict__ shift,      // [1]
    const int*   __restrict__ starts,     // [N+1]
    int M, int N,
    float* __restrict__ weights,          // [M]
    float* __restrict__ alphainv_last,    // [N]
    float* __restrict__ out3)             // [N,3]
{
    const int wave = (blockIdx.x * blockDim.x + threadIdx.x) >> 6;
    const int t    = threadIdx.x & 63;
    const int r0   = wave * RPW;
    if (r0 >= N) return;

    // Bounds for all RPW rays: one coalesced load, broadcast to SGPRs.
    const int bv = starts[min(r0 + t, N)];
    int s[RPW + 1];
    #pragma unroll
    for (int k = 0; k <= RPW; ++k)
        s[k] = __builtin_amdgcn_readlane(bv, k);

    const float sh = shift[0];
    const bool lowHalf = t < 32;

    // ---- Phase A: issue ALL loads up front (chunk0 x8, paired overflow x4) --
    float d0[RPW];  f3 c0v[RPW];
    float dP[NPAIR]; f3 cPv[NPAIR];
    int   iP[NPAIR];
    #pragma unroll
    for (int j = 0; j < RPW; ++j) {
        const int st = s[j], en = s[j + 1];
        const int c0 = max(min(st + t, en - 1), 0);
        d0[j]  = density[c0];
        c0v[j] = *(const f3*)(rgb_feat + 3 * c0);
    }
    #pragma unroll
    for (int p = 0; p < NPAIR; ++p) {
        // lane t<32: ray 2p sample st+64+t; lane t>=32: ray 2p+1 sample
        // st+64+(t-32) = st+32+t.
        const int idx = lowHalf ? (s[2 * p] + 64 + t) : (s[2 * p + 1] + 32 + t);
        const int en  = lowHalf ? s[2 * p + 1] : s[2 * p + 2];
        iP[p] = idx;
        const int c = max(min(idx, en - 1), 0);   // short ray -> clamped bcast
        dP[p]  = density[c];
        cPv[p] = *(const f3*)(rgb_feat + 3 * c);
    }
    // Keep-alive pins: loaded values must be simultaneously live here, so the
    // scheduler/regalloc cannot sink, split, or rematerialize the loads.
    __builtin_amdgcn_sched_barrier(0);
    asm volatile("" ::
        "v"(d0[0]), "v"(c0v[0].x), "v"(c0v[0].y), "v"(c0v[0].z),
        "v"(d0[1]), "v"(c0v[1].x), "v"(c0v[1].y), "v"(c0v[1].z),
        "v"(d0[2]), "v"(c0v[2].x), "v"(c0v[2].y), "v"(c0v[2].z),
        "v"(d0[3]), "v"(c0v[3].x), "v"(c0v[3].y), "v"(c0v[3].z),
        "v"(d0[4]), "v"(c0v[4].x), "v"(c0v[4].y), "v"(c0v[4].z),
        "v"(d0[5]), "v"(c0v[5].x), "v"(c0v[5].y), "v"(c0v[5].z),
        "v"(d0[6]), "v"(c0v[6].x), "v"(c0v[6].y), "v"(c0v[6].z),
        "v"(d0[7]), "v"(c0v[7].x), "v"(c0v[7].y), "v"(c0v[7].z));
    asm volatile("" ::
        "v"(dP[0]), "v"(cPv[0].x), "v"(cPv[0].y), "v"(cPv[0].z),
        "v"(dP[1]), "v"(cPv[1].x), "v"(cPv[1].y), "v"(cPv[1].z),
        "v"(dP[2]), "v"(cPv[2].x), "v"(cPv[2].y), "v"(cPv[2].z),
        "v"(dP[3]), "v"(cPv[3].x), "v"(cPv[3].y), "v"(cPv[3].z));
    __builtin_amdgcn_sched_barrier(0);

    float carryT[RPW], accR[RPW], accG[RPW], accB[RPW];

    // ---- Phase B: chunk-0 of all rays (8 independent chains, full ILP) ----
    #pragma unroll
    for (int j = 0; j < RPW; ++j) {
        const int st = s[j], en = s[j + 1];
        const bool valid = (st + t) < en;
        const float u = 1.0f + __expf(d0[j] + sh);
        const float a = __builtin_amdgcn_rsqf(u);      // 1 - alpha
        const float m = valid ? a : 1.0f;
        const float S = wave_scan_mul(m);              // inclusive product
        carryT[j] = bcast_lane63(S);
        const float w = S * (u * a - 1.0f);            // T_excl * alpha
        accR[j] = valid ? w * fast_sigmoid(c0v[j].x) : 0.0f;
        accG[j] = valid ? w * fast_sigmoid(c0v[j].y) : 0.0f;
        accB[j] = valid ? w * fast_sigmoid(c0v[j].z) : 0.0f;
        if (valid) weights[st + t] = w;
    }

    // ---- Phase C: paired overflow chunks (4 independent chains, branchless) -
    #pragma unroll
    for (int p = 0; p < NPAIR; ++p) {
        const int jA = 2 * p, jB = 2 * p + 1;
        const int en  = lowHalf ? s[jA + 1] : s[jB + 1];
        const int idx = iP[p];
        const bool valid = idx < en;
        const float u = 1.0f + __expf(dP[p] + sh);
        const float a = __builtin_amdgcn_rsqf(u);
        const float m = valid ? a : 1.0f;
        const float S = wave_scan_mul_half(m);         // segmented at lane 32
        const float totA = bcast_lane31(S);
        const float totB = bcast_lane63(S);
        const float carrySel = lowHalf ? carryT[jA] : carryT[jB];
        const float w = carrySel * S * (u * a - 1.0f);
        const float cR = valid ? w * fast_sigmoid(cPv[p].x) : 0.0f;
        const float cG = valid ? w * fast_sigmoid(cPv[p].y) : 0.0f;
        const float cB = valid ? w * fast_sigmoid(cPv[p].z) : 0.0f;
        accR[jA] += lowHalf ? cR : 0.0f;
        accG[jA] += lowHalf ? cG : 0.0f;
        accB[jA] += lowHalf ? cB : 0.0f;
        accR[jB] += lowHalf ? 0.0f : cR;
        accG[jB] += lowHalf ? 0.0f : cG;
        accB[jB] += lowHalf ? 0.0f : cB;
        if (valid) weights[idx] = w;
        carryT[jA] *= totA;
        carryT[jB] *= totB;
    }

    // ---- Phase D: len > 96 fallback (uniform branch; ~4 rays in 131072) ----
    #pragma unroll
    for (int j = 0; j < RPW; ++j) {
        const int st = s[j], en = s[j + 1];
        if (en - st > 96) {
            for (int base = st + 96; base < en; base += 64) {
                const int i = base + t;
                const bool v2 = i < en;
                const int c = min(i, en - 1);
                const float dd = density[c];
                const f3 cc = *(const f3*)(rgb_feat + 3 * c);
                const float u2 = 1.0f + __expf(dd + sh);
                const float a2 = __builtin_amdgcn_rsqf(u2);
                const float m2 = v2 ? a2 : 1.0f;
                const float S2 = wave_scan_mul(m2);
                const float tot2 = bcast_lane63(S2);
                const float w2 = carryT[j] * S2 * (u2 * a2 - 1.0f);
                if (v2) {
                    weights[i] = w2;
                    accR[j] += w2 * fast_sigmoid(cc.x);
                    accG[j] += w2 * fast_sigmoid(cc.y);
                    accB[j] += w2 * fast_sigmoid(cc.z);
                }
                carryT[j] *= tot2;
            }
        }
    }

    // ---- Phase E: epilogue — 24 independent DPP reduce chains, batched ----
    float tR[RPW], tG[RPW], tB[RPW];
    #pragma unroll
    for (int j = 0; j < RPW; ++j) {
        tR[j] = wave_scan_add(accR[j]);
        tG[j] = wave_scan_add(accG[j]);
        tB[j] = wave_scan_add(accB[j]);
    }
    #pragma unroll
    for (int j = 0; j < RPW; ++j) {
        const float sR = bcast_lane63(tR[j]);
        const float sG = bcast_lane63(tG[j]);
        const float sB = bcast_lane63(tB[j]);
        const int ray = r0 + j;
        if (t == 0 && ray < N) {
            alphainv_last[ray] = carryT[j];
            out3[3 * ray + 0] = sR + carryT[j];
            out3[3 * ray + 1] = sG + carryT[j];
            out3[3 * ray + 2] = sB + carryT[j];
        }
    }
}

extern "C" void kernel_launch(void* const* d_in, const int* in_sizes, int n_in,
                              void* d_out, int out_size, void* d_ws, size_t ws_size,
                              hipStream_t stream) {
    const float* density  = (const float*)d_in[0];
    const float* rgb_feat = (const float*)d_in[1];
    const float* shift    = (const float*)d_in[2];
    const int*   ray_id   = (const int*)d_in[3];

    const int M = in_sizes[0];
    const int N = (out_size - M) / 4;   // out_size = M + N + 3N

    float* weights       = (float*)d_out;
    float* alphainv_last = weights + M;
    float* out3          = alphainv_last + N;

    const int block = 256;
    int* starts = (int*)d_ws;

    const int M4 = M >> 2;
    const int grid_starts = (M4 + block - 1) / block;
    seg_starts4_kernel<<<grid_starts, block, 0, stream>>>(
        (const int4*)ray_id, M4, M, N, ray_id, starts);

    const int n_waves = (N + RPW - 1) / RPW;
    const int grid_render = (n_waves * 64 + block - 1) / block;
    favor_render_kernel<<<grid_render, block, 0, stream>>>(
        density, rgb_feat, shift, starts, M, N,
        weights, alphainv_last, out3);
}

// Round 7
// 210.786 us; speedup vs baseline: 1.0176x; 1.0176x over previous
//
#include <hip/hip_runtime.h>

// 1 - alpha = (1 + exp(density+shift))^(-0.5) = rsqrt(u), u = 1 + exp(x).
// w = T_excl * alpha = T_excl * (1 - a), a = rsqrt(u).

__device__ __forceinline__ float fast_sigmoid(float x) {
    return __builtin_amdgcn_rcpf(1.0f + __expf(-x));
}

struct __align__(4) f3 { float x, y, z; };   // 12B, 4B-aligned
struct __align__(4) f2 { float x, y; };      // 8B, 4B-aligned

// ---- DPP wave64 scans ------------------------------------------------------
#define DPP_ADD(x, ctrl, rmask)                                               \
    do {                                                                      \
        int _s = __builtin_amdgcn_update_dpp(0, __float_as_int(x), (ctrl),    \
                                             (rmask), 0xf, true);             \
        (x) += __int_as_float(_s);                                            \
    } while (0)

#define DPP_MUL(x, ctrl, rmask)                                               \
    do {                                                                      \
        int _s = __builtin_amdgcn_update_dpp(0x3f800000, __float_as_int(x),   \
                                             (ctrl), (rmask), 0xf, false);    \
        (x) *= __int_as_float(_s);                                            \
    } while (0)

__device__ __forceinline__ float wave_scan_add(float x) {
    DPP_ADD(x, 0x111, 0xf);  // row_shr:1
    DPP_ADD(x, 0x112, 0xf);  // row_shr:2
    DPP_ADD(x, 0x114, 0xf);  // row_shr:4
    DPP_ADD(x, 0x118, 0xf);  // row_shr:8
    DPP_ADD(x, 0x142, 0xa);  // row_bcast:15 -> rows 1,3
    DPP_ADD(x, 0x143, 0xc);  // row_bcast:31 -> rows 2,3
    return x;
}

// Full-wave inclusive product scan.
__device__ __forceinline__ float wave_scan_mul(float x) {
    DPP_MUL(x, 0x111, 0xf);
    DPP_MUL(x, 0x112, 0xf);
    DPP_MUL(x, 0x114, 0xf);
    DPP_MUL(x, 0x118, 0xf);
    DPP_MUL(x, 0x142, 0xa);
    DPP_MUL(x, 0x143, 0xc);
    return x;
}

// Wave-wide shift-right-by-1 with multiplicative identity into lane 0:
// converts an inclusive scan into an exclusive one. DPP ctrl 0x138 =
// wave_shr:1 (gfx9/CDNA keeps wave-wide DPP shifts; bound_ctrl=false ->
// invalid lane 0 reads the 'old' operand = 1.0f).
__device__ __forceinline__ float dpp_excl_from_incl(float x) {
    int r = __builtin_amdgcn_update_dpp(0x3f800000, __float_as_int(x),
                                        0x138, 0xf, 0xf, false);
    return __int_as_float(r);
}

__device__ __forceinline__ float bcast_lane63(float x) {
    return __int_as_float(__builtin_amdgcn_readlane(__float_as_int(x), 63));
}

// ---- Pass 1: segment starts (int4-vectorized boundary detection) -----------
__global__ __launch_bounds__(256) void seg_starts4_kernel(
    const int4* __restrict__ ray4, int M4, int M, int N,
    const int* __restrict__ ray_id, int* __restrict__ starts)
{
    const int i = blockIdx.x * blockDim.x + threadIdx.x;
    if (i >= M4) return;
    const int4 v = ray4[i];
    const int prev = (i == 0) ? -1 : ray_id[4 * i - 1];
    const int base = 4 * i;
    for (int r = prev + 1; r <= v.x; ++r) starts[r] = base;
    for (int r = v.x + 1;  r <= v.y; ++r) starts[r] = base + 1;
    for (int r = v.y + 1;  r <= v.z; ++r) starts[r] = base + 2;
    for (int r = v.z + 1;  r <= v.w; ++r) starts[r] = base + 3;
    if (i == M4 - 1) {
        int last = v.w;
        for (int j = 4 * M4; j < M; ++j) {      // scalar tail (M%4)
            const int cur = ray_id[j];
            for (int r = last + 1; r <= cur; ++r) starts[r] = j;
            last = cur;
        }
        for (int r = last + 1; r <= N; ++r) starts[r] = M;
    }
}

// ---- Pass 2: RPW rays per wave, 2 samples per lane = ONE scan per ray ------
// R0-R6 falsified every scheduling lever (time ~60-65us invariant to work
// +-33%, pinning, ILP depth, occupancy 40-70%). Remaining structure: the
// per-ray chunk0 -> carry -> overflow serial chain. Removed here: lane t
// covers samples st+2t, st+2t+1 -> 128 slots per scan; ray lengths are
// ~Binomial(M,1/N) (max over 131072 rays ~103 < 128), so EVERY ray needs
// exactly one scan. Exclusive prefix via one wave_shr:1 DPP. No carry, no
// Phase C, scans/wave 6->4, fewer loads/stores. len>128 keeps a (never
// taken in practice) full-wave carry-loop fallback.
#define RPW 4

__global__ __launch_bounds__(256, 4) void favor_render_kernel(
    const float* __restrict__ density,
    const float* __restrict__ rgb_feat,   // [M,3]
    const float* __restrict__ shift,      // [1]
    const int*   __restrict__ starts,     // [N+1]
    int M, int N,
    float* __restrict__ weights,          // [M]
    float* __restrict__ alphainv_last,    // [N]
    float* __restrict__ out3)             // [N,3]
{
    const int wave = (blockIdx.x * blockDim.x + threadIdx.x) >> 6;
    const int t    = threadIdx.x & 63;
    const int r0   = wave * RPW;
    if (r0 >= N) return;

    // Bounds for all RPW rays: one coalesced load, broadcast to SGPRs.
    const int bv = starts[min(r0 + t, N)];
    int s[RPW + 1];
    #pragma unroll
    for (int k = 0; k <= RPW; ++k)
        s[k] = __builtin_amdgcn_readlane(bv, k);

    const float sh = shift[0];

    // ---- Phase A: loads (2 samples per lane per ray, clamped in-bounds) ----
    float dA[RPW], dB[RPW];
    f3 cA[RPW], cB[RPW];
    #pragma unroll
    for (int j = 0; j < RPW; ++j) {
        const int st = s[j], en = s[j + 1];
        const int i0 = st + 2 * t;
        const int c0 = max(min(i0,     en - 1), 0);
        const int c1 = max(min(i0 + 1, en - 1), 0);
        dA[j] = density[c0];
        dB[j] = density[c1];
        cA[j] = *(const f3*)(rgb_feat + 3 * c0);
        cB[j] = *(const f3*)(rgb_feat + 3 * c1);
    }

    float carryT[RPW], accR[RPW], accG[RPW], accB[RPW];

    // ---- Phase B: one pair-scan per ray (RPW independent chains) ----
    #pragma unroll
    for (int j = 0; j < RPW; ++j) {
        const int st = s[j], en = s[j + 1];
        const int i0 = st + 2 * t;
        const bool v0 = i0 < en;
        const bool v1 = (i0 + 1) < en;

        const float u0 = 1.0f + __expf(dA[j] + sh);
        const float u1 = 1.0f + __expf(dB[j] + sh);
        const float a0r = __builtin_amdgcn_rsqf(u0);   // 1 - alpha0
        const float a1r = __builtin_amdgcn_rsqf(u1);
        const float a0 = v0 ? a0r : 1.0f;
        const float a1 = v1 ? a1r : 1.0f;
        const float m  = a0 * a1;                      // pair product

        const float S = wave_scan_mul(m);              // inclusive over pairs
        const float E = dpp_excl_from_incl(S);         // T_excl before sample0
        carryT[j] = bcast_lane63(S);                   // ray total (1-alpha)prod

        const float w0 = E * (1.0f - a0);              // 0 when !v0 (a0==1)
        const float w1 = (E * a0) * (1.0f - a1);       // 0 when !v1

        // acc: w==0 already masks invalid lanes; sigmoid(finite)=finite.
        accR[j] = w0 * fast_sigmoid(cA[j].x) + w1 * fast_sigmoid(cB[j].x);
        accG[j] = w0 * fast_sigmoid(cA[j].y) + w1 * fast_sigmoid(cB[j].y);
        accB[j] = w0 * fast_sigmoid(cA[j].z) + w1 * fast_sigmoid(cB[j].z);

        if (v1) {                    // both samples valid: one dwordx2
            f2 wv; wv.x = w0; wv.y = w1;
            *(f2*)(weights + i0) = wv;
        } else if (v0) {             // boundary lane: single scalar
            weights[i0] = w0;
        }
    }

    // ---- Phase D: len > 128 fallback (uniform branch; never in practice) ----
    #pragma unroll
    for (int j = 0; j < RPW; ++j) {
        const int st = s[j], en = s[j + 1];
        if (en - st > 128) {
            for (int base = st + 128; base < en; base += 64) {
                const int i = base + t;
                const bool v2 = i < en;
                const int c = min(i, en - 1);
                const float dd = density[c];
                const f3 cc = *(const f3*)(rgb_feat + 3 * c);
                const float u2 = 1.0f + __expf(dd + sh);
                const float a2 = __builtin_amdgcn_rsqf(u2);
                const float m2 = v2 ? a2 : 1.0f;
                const float S2 = wave_scan_mul(m2);
                const float tot2 = bcast_lane63(S2);
                const float w2 = carryT[j] * S2 * (u2 * a2 - 1.0f);
                if (v2) {
                    weights[i] = w2;
                    accR[j] += w2 * fast_sigmoid(cc.x);
                    accG[j] += w2 * fast_sigmoid(cc.y);
                    accB[j] += w2 * fast_sigmoid(cc.z);
                }
                carryT[j] *= tot2;
            }
        }
    }

    // ---- Phase E: epilogue — 12 independent DPP reduce chains, batched;
    //      stores from lanes 0..RPW-1 (coalesced-ish, 2 insts vs 16) ----
    float sR[RPW], sG[RPW], sB[RPW];
    #pragma unroll
    for (int j = 0; j < RPW; ++j) {
        sR[j] = bcast_lane63(wave_scan_add(accR[j]));
        sG[j] = bcast_lane63(wave_scan_add(accG[j]));
        sB[j] = bcast_lane63(wave_scan_add(accB[j]));
    }
    if (t < RPW) {
        const int ray = r0 + t;
        if (ray < N) {
            const float vT = (t == 0) ? carryT[0] : (t == 1) ? carryT[1]
                           : (t == 2) ? carryT[2] : carryT[3];
            const float vR = (t == 0) ? sR[0] : (t == 1) ? sR[1]
                           : (t == 2) ? sR[2] : sR[3];
            const float vG = (t == 0) ? sG[0] : (t == 1) ? sG[1]
                           : (t == 2) ? sG[2] : sG[3];
            const float vB = (t == 0) ? sB[0] : (t == 1) ? sB[1]
                           : (t == 2) ? sB[2] : sB[3];
            alphainv_last[ray] = vT;
            f3 o; o.x = vR + vT; o.y = vG + vT; o.z = vB + vT;
            *(f3*)(out3 + 3 * ray) = o;
        }
    }
}

extern "C" void kernel_launch(void* const* d_in, const int* in_sizes, int n_in,
                              void* d_out, int out_size, void* d_ws, size_t ws_size,
                              hipStream_t stream) {
    const float* density  = (const float*)d_in[0];
    const float* rgb_feat = (const float*)d_in[1];
    const float* shift    = (const float*)d_in[2];
    const int*   ray_id   = (const int*)d_in[3];

    const int M = in_sizes[0];
    const int N = (out_size - M) / 4;   // out_size = M + N + 3N

    float* weights       = (float*)d_out;
    float* alphainv_last = weights + M;
    float* out3          = alphainv_last + N;

    const int block = 256;
    int* starts = (int*)d_ws;

    const int M4 = M >> 2;
    const int grid_starts = (M4 + block - 1) / block;
    seg_starts4_kernel<<<grid_starts, block, 0, stream>>>(
        (const int4*)ray_id, M4, M, N, ray_id, starts);

    const int n_waves = (N + RPW - 1) / RPW;
    const int grid_render = (n_waves * 64 + block - 1) / block;
    favor_render_kernel<<<grid_render, block, 0, stream>>>(
        density, rgb_feat, shift, starts, M, N,
        weights, alphainv_last, out3);
}